// Round 9
// baseline (100.833 us; speedup 1.0000x reference)
//
#include <hip/hip_runtime.h>
#include <math.h>

#define S_TOTAL 4096
#define DDIM    512
#define AXES    72
#define NPROJ   864
#define T_PROP  600
#define SA      (S_TOTAL*AXES)
#define LN_EPS  1e-5f
#define AMP_CUT 4e-6f

typedef __attribute__((ext_vector_type(8))) short short8;
typedef __attribute__((ext_vector_type(4))) float f32x4;

__device__ __forceinline__ float softplus_f(float x) {
    return fmaxf(x, 0.f) + log1pf(expf(-fabsf(x)));
}
__device__ __forceinline__ unsigned short bf_hi(float f) {
    return (unsigned short)(__float_as_uint(f) >> 16);
}

// ---------------- 1. fused LN-stats + bf16 split + W^T split + kin zero ----------------
// block ranges: [0,1024) xn rows, [1024,1456) W tiles, [1456,1492) zero kin
__global__ __launch_bounds__(256) void prep_kernel(
        const float* __restrict__ x, const float* __restrict__ gamma,
        const float* __restrict__ beta, const float* __restrict__ W,
        unsigned short* __restrict__ Ahi, unsigned short* __restrict__ Alo,
        unsigned short* __restrict__ WhiT, unsigned short* __restrict__ WloT,
        float* __restrict__ kin) {
    __shared__ float Wt[32][33];
    int tid = threadIdx.x;
    int b = blockIdx.x;
    if (b < 1024) {
        int lane = tid & 63, w = tid >> 6;
        int row = b*4 + w;
        const float4* xr = reinterpret_cast<const float4*>(x + (size_t)row * DDIM);
        float4 xv[2] = { xr[lane], xr[lane + 64] };
        float sum = 0.f, ssq = 0.f;
#pragma unroll
        for (int c = 0; c < 2; ++c) {
            sum += (xv[c].x + xv[c].y) + (xv[c].z + xv[c].w);
            ssq += xv[c].x*xv[c].x + xv[c].y*xv[c].y + xv[c].z*xv[c].z + xv[c].w*xv[c].w;
        }
#pragma unroll
        for (int off = 1; off < 64; off <<= 1) {
            sum += __shfl_xor(sum, off);
            ssq += __shfl_xor(ssq, off);
        }
        float m = sum * (1.f/DDIM);
        float r = rsqrtf(ssq * (1.f/DDIM) - m*m + LN_EPS);
        const float4* gp = reinterpret_cast<const float4*>(gamma);
        const float4* bp = reinterpret_cast<const float4*>(beta);
#pragma unroll
        for (int c = 0; c < 2; ++c) {
            float4 gv = gp[lane + 64*c], bv = bp[lane + 64*c];
            float xn[4] = {(xv[c].x-m)*r*gv.x+bv.x, (xv[c].y-m)*r*gv.y+bv.y,
                           (xv[c].z-m)*r*gv.z+bv.z, (xv[c].w-m)*r*gv.w+bv.w};
            ushort4 h4, l4;
            unsigned short* hp = &h4.x;
            unsigned short* lp = &l4.x;
#pragma unroll
            for (int j = 0; j < 4; ++j) {
                unsigned short hi = bf_hi(xn[j]);
                float fhi = __uint_as_float((unsigned)hi << 16);
                hp[j] = hi;
                lp[j] = bf_hi(xn[j] - fhi);
            }
            size_t o = (size_t)row*DDIM + 256*c + lane*4;
            *reinterpret_cast<ushort4*>(&Ahi[o]) = h4;
            *reinterpret_cast<ushort4*>(&Alo[o]) = l4;
        }
    } else if (b < 1456) {
        int wb = b - 1024;
        int bk = wb / 27, bn = wb - bk*27;
        int tx = tid & 31, ty0 = tid >> 5;
#pragma unroll
        for (int rr = 0; rr < 4; ++rr) {
            int ty = ty0 + rr*8;
            Wt[ty][tx] = W[(size_t)(bk*32 + ty)*NPROJ + bn*32 + tx];
        }
        __syncthreads();
#pragma unroll
        for (int rr = 0; rr < 4; ++rr) {
            int ny = ty0 + rr*8;
            int n = bn*32 + ny;
            int k = bk*32 + tx;
            float f = Wt[tx][ny];
            unsigned short hi = bf_hi(f);
            float fhi = __uint_as_float((unsigned)hi << 16);
            WhiT[(size_t)n*DDIM + k] = hi;
            WloT[(size_t)n*DDIM + k] = bf_hi(f - fhi);
        }
    } else {
        // zero kinematics plane: 36 blocks x 256 threads x 8 float4 = 294912 floats
        int zb = b - 1456;
        float4 z4 = make_float4(0.f, 0.f, 0.f, 0.f);
        float4* kp = reinterpret_cast<float4*>(kin);
#pragma unroll
        for (int i = 0; i < 8; ++i)
            kp[zb*2048 + i*256 + tid] = z4;
    }
}

// ---------------- 2. split-bf16 MFMA GEMM, LDS-FREE (direct L2 fragment loads) ----------------
// Operands are L2/L3-resident (A 16MB, W^T 3.4MB). Each lane loads its MFMA
// fragment short8 directly: row(l15)*512 + g*8 -- the 4 g-lanes of a row share
// one 64B sector, so loads are sector-perfect. No LDS, no barriers, no
// staging registers; 10 independent loads per k-step hide L2 latency at
// high occupancy. Grid (n-blocks, s-blocks) so adjacent blocks share A rows.
__global__ __launch_bounds__(256) void gemm_kernel(
        const unsigned short* __restrict__ Ahi, const unsigned short* __restrict__ Alo,
        const unsigned short* __restrict__ WhiT, const unsigned short* __restrict__ WloT,
        const float* __restrict__ bias,
        float* __restrict__ P, float* __restrict__ out) {
    int tid  = threadIdx.x;
    int lane = tid & 63;
    int wv   = tid >> 6;
    int wm   = wv & 1;
    int wn   = wv >> 1;
    int nBase = blockIdx.x * 96;
    int sBase = blockIdx.y * 64;
    int l15 = lane & 15;
    int g   = lane >> 4;

    const short8* xb[2][2];   // [hi/lo][mi]
    const short8* wb[2][3];   // [hi/lo][nf]
#pragma unroll
    for (int mi = 0; mi < 2; ++mi) {
        size_t o = (size_t)(sBase + wm*32 + mi*16 + l15) * DDIM + g*8;
        xb[0][mi] = reinterpret_cast<const short8*>(Ahi + o);
        xb[1][mi] = reinterpret_cast<const short8*>(Alo + o);
    }
#pragma unroll
    for (int nf = 0; nf < 3; ++nf) {
        size_t o = (size_t)(nBase + wn*48 + nf*16 + l15) * DDIM + g*8;
        wb[0][nf] = reinterpret_cast<const short8*>(WhiT + o);
        wb[1][nf] = reinterpret_cast<const short8*>(WloT + o);
    }

    f32x4 acc[2][3] = {};

#pragma unroll 2
    for (int kt = 0; kt < 16; ++kt) {
        int ko = kt * 4;                 // in short8 units: 32 k-elems per step
        short8 xh[2], xl[2], wh[3], wl[3];
#pragma unroll
        for (int mi = 0; mi < 2; ++mi) {
            xh[mi] = xb[0][mi][ko];
            xl[mi] = xb[1][mi][ko];
        }
#pragma unroll
        for (int nf = 0; nf < 3; ++nf) {
            wh[nf] = wb[0][nf][ko];
            wl[nf] = wb[1][nf][ko];
        }
#pragma unroll
        for (int mi = 0; mi < 2; ++mi)
#pragma unroll
            for (int nf = 0; nf < 3; ++nf)
                acc[mi][nf] = __builtin_amdgcn_mfma_f32_16x16x32_bf16(wh[nf], xh[mi], acc[mi][nf], 0, 0, 0);
#pragma unroll
        for (int mi = 0; mi < 2; ++mi)
#pragma unroll
            for (int nf = 0; nf < 3; ++nf)
                acc[mi][nf] = __builtin_amdgcn_mfma_f32_16x16x32_bf16(wh[nf], xl[mi], acc[mi][nf], 0, 0, 0);
#pragma unroll
        for (int mi = 0; mi < 2; ++mi)
#pragma unroll
            for (int nf = 0; nf < 3; ++nf)
                acc[mi][nf] = __builtin_amdgcn_mfma_f32_16x16x32_bf16(wl[nf], xh[mi], acc[mi][nf], 0, 0, 0);
    }

    // epilogue: D rows = n, D cols = s (coalesced)
    int sCol = sBase + wm*32 + l15;
    int nRowBase = nBase + wn*48 + (g<<2);
#pragma unroll
    for (int mi = 0; mi < 2; ++mi) {
        int s = sCol + mi*16;
#pragma unroll
        for (int nf = 0; nf < 3; ++nf) {
#pragma unroll
            for (int r = 0; r < 4; ++r) {
                int n = nRowBase + nf*16 + r;
                float val = acc[mi][nf][r] + bias[n];
                int ip = (n * 3641) >> 18;   // n / 72
                int a  = n - ip * 72;
                float res;
                if (ip == 0 || ip == 2)      res = sqrtf(softplus_f(val));
                else if (ip == 1 || ip == 3 || ip == 9 || ip == 11) res = softplus_f(val);
                else                          res = val;
                float* dst = (ip < 8) ? (P + (size_t)ip * SA)
                                      : (out + (size_t)(ip - 7) * SA);
                dst[(size_t)a * S_TOTAL + s] = res;
            }
        }
    }
}

// ---------------- 3. oscillator: order-2 recurrences + rotation scatter ----------------
template<int STEPS>
__device__ __forceinline__ void osc_chunk(
        float& v1a, float& v1b, float& v2a, float& v2b,
        float p1, float q1, float p2, float q2,
        float& acc0, float& acc1, int lane, int lane4) {
#pragma unroll
    for (int i = 0; i < STEPS/2; ++i) {
        {
            const int dt = 2*i;
            v1b = fmaf(p1, v1a, -(q1*v1b));
            v2b = fmaf(p2, v2a, -(q2*v2b));
            float v = v1b + v2b;
            if (dt == 0) {
                acc0 += v;
            } else {
                int addr = (lane4 + (((64-dt)&63)<<2)) & 255;
                float vr = __int_as_float(__builtin_amdgcn_ds_bpermute(addr, __float_as_int(v)));
                bool nw = lane >= dt;
                acc0 += nw ? vr : 0.f;
                acc1 += nw ? 0.f : vr;
            }
        }
        {
            const int dt = 2*i + 1;
            v1a = fmaf(p1, v1b, -(q1*v1a));
            v2a = fmaf(p2, v2b, -(q2*v2a));
            float v = v1a + v2a;
            int addr = (lane4 + (((64-dt)&63)<<2)) & 255;
            float vr = __int_as_float(__builtin_amdgcn_ds_bpermute(addr, __float_as_int(v)));
            bool nw = lane >= dt;
            acc0 += nw ? vr : 0.f;
            acc1 += nw ? 0.f : vr;
        }
    }
}

__global__ __launch_bounds__(256) void osc_kernel(const float* __restrict__ P,
                                                  float* __restrict__ kin) {
    int tid  = threadIdx.x;
    int lane = tid & 63;
    int wv   = tid >> 6;
    int lane4 = lane << 2;
    int sBase = blockIdx.x * 64;
    int a  = blockIdx.y * 2 + (wv >> 1);
    int t0 = (wv & 1) * 300;
    float t0f = (float)t0;

    size_t base = (size_t)a * S_TOTAL + sBase + lane;
    float om1 = P[0*(size_t)SA + base], d1 = P[1*(size_t)SA + base];
    float om2 = P[2*(size_t)SA + base], d2 = P[3*(size_t)SA + base];
    float c1  = P[4*(size_t)SA + base], c2  = P[5*(size_t)SA + base];
    float ph1 = P[6*(size_t)SA + base], ph2 = P[7*(size_t)SA + base];

    float dcf1 = __expf(-0.5f*d1);
    float e1   = c1 * __expf(-0.5f*d1*t0f);
    float s0, c0, so, co;
    __sincosf(fmaf(t0f, om1, ph1), &s0, &c0);
    __sincosf(om1, &so, &co);
    float inv1 = __expf(0.5f*d1);
    float p1 = 2.f*dcf1*co, q1 = dcf1*dcf1;
    float v1a = e1*inv1*(s0*co - c0*so);
    float cs2 = fmaf(2.f*co, co, -1.f), sn2 = 2.f*so*co;
    float v1b = e1*inv1*inv1*(s0*cs2 - c0*sn2);
    float amp1 = fabsf(e1);
    float dq1 = q1*q1; dq1*=dq1; dq1*=dq1; dq1*=dq1; dq1*=dq1;
    float dcf2 = __expf(-0.5f*d2);
    float e2   = c2 * __expf(-0.5f*d2*t0f);
    __sincosf(fmaf(t0f, om2, ph2), &s0, &c0);
    __sincosf(om2, &so, &co);
    float inv2 = __expf(0.5f*d2);
    float p2 = 2.f*dcf2*co, q2 = dcf2*dcf2;
    float v2a = e2*inv2*(s0*co - c0*so);
    cs2 = fmaf(2.f*co, co, -1.f); sn2 = 2.f*so*co;
    float v2b = e2*inv2*inv2*(s0*cs2 - c0*sn2);
    float amp2 = fabsf(e2);
    float dq2 = q2*q2; dq2*=dq2; dq2*=dq2; dq2*=dq2; dq2*=dq2;

    float acc0 = 0.f, acc1 = 0.f;
    float* kinA = kin + (size_t)a * S_TOTAL;
    int jBase = sBase + t0;
    int ran = 0;

#pragma unroll 1
    for (int c = 0; c < 5; ++c) {
        if (__all(fmaxf(amp1, amp2) < AMP_CUT)) break;
        if (c < 4) osc_chunk<64>(v1a, v1b, v2a, v2b, p1, q1, p2, q2, acc0, acc1, lane, lane4);
        else       osc_chunk<44>(v1a, v1b, v2a, v2b, p1, q1, p2, q2, acc0, acc1, lane, lane4);
        int j = jBase + lane;
        if (j < S_TOTAL) unsafeAtomicAdd(&kinA[j], acc0);
        acc0 = acc1; acc1 = 0.f;
        jBase += 64;
        amp1 *= dq1; amp2 *= dq2;
        ran = 1;
        if (jBase >= S_TOTAL) { ran = 0; break; }
    }
    if (ran) {
        int j = jBase + lane;
        if (j < S_TOTAL) unsafeAtomicAdd(&kinA[j], acc0);
    }
}

// ---------------- launch ----------------
extern "C" void kernel_launch(void* const* d_in, const int* in_sizes, int n_in,
                              void* d_out, int out_size, void* d_ws, size_t ws_size,
                              hipStream_t stream) {
    const float* x     = (const float*)d_in[0];
    const float* gamma = (const float*)d_in[1];
    const float* beta  = (const float*)d_in[2];
    const float* W     = (const float*)d_in[3];
    const float* b     = (const float*)d_in[4];
    float* out = (float*)d_out;

    unsigned char* wsb = (unsigned char*)d_ws;
    float* P    = (float*)wsb;                               // 8*SA f32
    unsigned short* Ahi  = (unsigned short*)(wsb + 9437184);
    unsigned short* Alo  = Ahi  + (size_t)S_TOTAL*DDIM;
    unsigned short* WhiT = Alo  + (size_t)S_TOTAL*DDIM;
    unsigned short* WloT = WhiT + (size_t)NPROJ*DDIM;

    prep_kernel<<<dim3(1024 + 432 + 36), dim3(256), 0, stream>>>(x, gamma, beta, W,
                                                                 Ahi, Alo, WhiT, WloT, out);
    gemm_kernel<<<dim3(NPROJ/96, S_TOTAL/64), dim3(256), 0, stream>>>(Ahi, Alo, WhiT, WloT,
                                                                      b, P, out);
    osc_kernel<<<dim3(S_TOTAL/64, AXES/2), dim3(256), 0, stream>>>(P, out);
}

// Round 10
// 64.472 us; speedup vs baseline: 1.5640x; 1.5640x over previous
//
#include <hip/hip_runtime.h>
#include <math.h>

#define S_TOTAL 4096
#define DDIM    512
#define AXES    72
#define NPROJ   864
#define T_PROP  600
#define SA      (S_TOTAL*AXES)
#define LN_EPS  1e-5f
#define AMP_CUT 4e-6f

typedef __attribute__((ext_vector_type(8))) short short8;
typedef __attribute__((ext_vector_type(4))) float f32x4;

__device__ __forceinline__ float softplus_f(float x) {
    return fmaxf(x, 0.f) + log1pf(expf(-fabsf(x)));
}
__device__ __forceinline__ unsigned short bf_hi(float f) {
    return (unsigned short)(__float_as_uint(f) >> 16);
}

// ---------------- 1. fused LN-stats + bf16 split + W^T split + kin zero ----------------
__global__ __launch_bounds__(256) void prep_kernel(
        const float* __restrict__ x, const float* __restrict__ gamma,
        const float* __restrict__ beta, const float* __restrict__ W,
        unsigned short* __restrict__ Ahi, unsigned short* __restrict__ Alo,
        unsigned short* __restrict__ WhiT, unsigned short* __restrict__ WloT,
        float* __restrict__ kin) {
    __shared__ float Wt[32][33];
    int tid = threadIdx.x;
    int b = blockIdx.x;
    if (b < 1024) {
        int lane = tid & 63, w = tid >> 6;
        int row = b*4 + w;
        const float4* xr = reinterpret_cast<const float4*>(x + (size_t)row * DDIM);
        float4 xv[2] = { xr[lane], xr[lane + 64] };
        float sum = 0.f, ssq = 0.f;
#pragma unroll
        for (int c = 0; c < 2; ++c) {
            sum += (xv[c].x + xv[c].y) + (xv[c].z + xv[c].w);
            ssq += xv[c].x*xv[c].x + xv[c].y*xv[c].y + xv[c].z*xv[c].z + xv[c].w*xv[c].w;
        }
#pragma unroll
        for (int off = 1; off < 64; off <<= 1) {
            sum += __shfl_xor(sum, off);
            ssq += __shfl_xor(ssq, off);
        }
        float m = sum * (1.f/DDIM);
        float r = rsqrtf(ssq * (1.f/DDIM) - m*m + LN_EPS);
        const float4* gp = reinterpret_cast<const float4*>(gamma);
        const float4* bp = reinterpret_cast<const float4*>(beta);
#pragma unroll
        for (int c = 0; c < 2; ++c) {
            float4 gv = gp[lane + 64*c], bv = bp[lane + 64*c];
            float xn[4] = {(xv[c].x-m)*r*gv.x+bv.x, (xv[c].y-m)*r*gv.y+bv.y,
                           (xv[c].z-m)*r*gv.z+bv.z, (xv[c].w-m)*r*gv.w+bv.w};
            ushort4 h4, l4;
            unsigned short* hp = &h4.x;
            unsigned short* lp = &l4.x;
#pragma unroll
            for (int j = 0; j < 4; ++j) {
                unsigned short hi = bf_hi(xn[j]);
                float fhi = __uint_as_float((unsigned)hi << 16);
                hp[j] = hi;
                lp[j] = bf_hi(xn[j] - fhi);
            }
            size_t o = (size_t)row*DDIM + 256*c + lane*4;
            *reinterpret_cast<ushort4*>(&Ahi[o]) = h4;
            *reinterpret_cast<ushort4*>(&Alo[o]) = l4;
        }
    } else if (b < 1456) {
        int wb = b - 1024;
        int bk = wb / 27, bn = wb - bk*27;
        int tx = tid & 31, ty0 = tid >> 5;
#pragma unroll
        for (int rr = 0; rr < 4; ++rr) {
            int ty = ty0 + rr*8;
            Wt[ty][tx] = W[(size_t)(bk*32 + ty)*NPROJ + bn*32 + tx];
        }
        __syncthreads();
#pragma unroll
        for (int rr = 0; rr < 4; ++rr) {
            int ny = ty0 + rr*8;
            int n = bn*32 + ny;
            int k = bk*32 + tx;
            float f = Wt[tx][ny];
            unsigned short hi = bf_hi(f);
            float fhi = __uint_as_float((unsigned)hi << 16);
            WhiT[(size_t)n*DDIM + k] = hi;
            WloT[(size_t)n*DDIM + k] = bf_hi(f - fhi);
        }
    } else {
        int zb = b - 1456;
        float4 z4 = make_float4(0.f, 0.f, 0.f, 0.f);
        float4* kp = reinterpret_cast<float4*>(kin);
#pragma unroll
        for (int i = 0; i < 8; ++i)
            kp[zb*2048 + i*256 + tid] = z4;
    }
}

// ---------------- 2. split-bf16 MFMA GEMM: global_load_lds + counted-vmcnt pipeline ----------------
// R8 structure + T3/T4: two LDS buffers staged 2-deep, per k-step
// s_waitcnt vmcnt(10) (only the OLDEST buffer's 10 loads) + raw s_barrier,
// so prefetch loads stay in flight across barriers (never drain to 0 until
// the last step). LDS layout per buffer (bytes): Xhi[0,8K) Xlo[8K,16K)
// Whi[16K,28K) Wlo[28K,40K); XOR swizzle via pre-swizzled global source.
__global__ __launch_bounds__(256) void gemm_kernel(
        const unsigned short* __restrict__ Ahi, const unsigned short* __restrict__ Alo,
        const unsigned short* __restrict__ WhiT, const unsigned short* __restrict__ WloT,
        const float* __restrict__ bias,
        float* __restrict__ P, float* __restrict__ out) {
    __shared__ __align__(16) unsigned short ldsArena[2*20480];   // 80 KB

    int tid  = threadIdx.x;
    int lane = tid & 63;
    int wv   = tid >> 6;
    int wm   = wv & 1;
    int wn   = wv >> 1;
    int sBase = blockIdx.x * 64;
    int nBase = blockIdx.y * 96;
    int l15 = lane & 15;
    int g   = lane >> 4;       // 0..3
    int r7  = l15 & 7;

    // stage sources: lane (rr, l7) of segment seg reads global k-slot (l7^rr)
    int rr = lane >> 3;
    int jj = ((lane & 7) ^ rr) * 8;
    const unsigned short* gp[10];
#pragma unroll
    for (int sg = 0; sg < 10; ++sg) {
        int seg = wv*10 + sg;
        const unsigned short* src;
        int row;
        if (seg < 16) {
            int p = seg >> 3, rg = seg & 7;
            row = sBase + rg*8 + rr;
            src = p ? Alo : Ahi;
        } else {
            int s2 = seg - 16;
            int p = (s2 >= 12) ? 1 : 0, rg = s2 - p*12;
            row = nBase + rg*8 + rr;
            src = p ? WloT : WhiT;
        }
        gp[sg] = src + (size_t)row*DDIM + jj;
    }

    // precomputed swizzled ds_read offsets
    int koff0 = (g*16) ^ (r7<<4);
    int koff1 = (64 + g*16) ^ (r7<<4);
    int rowXb[2], rowWb[3];
#pragma unroll
    for (int mi = 0; mi < 2; ++mi) rowXb[mi] = (wm*32 + mi*16 + l15) * 128;
#pragma unroll
    for (int nf = 0; nf < 3; ++nf) rowWb[nf] = (wn*48 + nf*16 + l15) * 128;

    f32x4 acc[2][3] = {};

#define STAGE(buf, kt) do {                                                   \
        unsigned short* lb = ldsArena + (buf)*20480 + wv*5120;                \
        _Pragma("unroll")                                                     \
        for (int sg = 0; sg < 10; ++sg)                                       \
            __builtin_amdgcn_global_load_lds(                                 \
                (const __attribute__((address_space(1))) void*)(gp[sg] + (kt)*64), \
                (__attribute__((address_space(3))) void*)(lb + sg*512),       \
                16, 0, 0);                                                    \
    } while (0)

#define COMPUTE(BUF) do {                                                     \
        const char* Bc = (const char*)ldsArena + (BUF)*40960;                 \
        _Pragma("unroll")                                                     \
        for (int kk = 0; kk < 2; ++kk) {                                      \
            int ko = kk ? koff1 : koff0;                                      \
            short8 xh[2], xl[2], wh[3], wl[3];                                \
            _Pragma("unroll")                                                 \
            for (int mi = 0; mi < 2; ++mi) {                                  \
                xh[mi] = *reinterpret_cast<const short8*>(Bc + rowXb[mi] + ko);        \
                xl[mi] = *reinterpret_cast<const short8*>(Bc + 8192 + rowXb[mi] + ko); \
            }                                                                 \
            _Pragma("unroll")                                                 \
            for (int nf = 0; nf < 3; ++nf) {                                  \
                wh[nf] = *reinterpret_cast<const short8*>(Bc + 16384 + rowWb[nf] + ko); \
                wl[nf] = *reinterpret_cast<const short8*>(Bc + 28672 + rowWb[nf] + ko); \
            }                                                                 \
            _Pragma("unroll")                                                 \
            for (int mi = 0; mi < 2; ++mi)                                    \
                _Pragma("unroll")                                             \
                for (int nf = 0; nf < 3; ++nf)                                \
                    acc[mi][nf] = __builtin_amdgcn_mfma_f32_16x16x32_bf16(wh[nf], xh[mi], acc[mi][nf], 0, 0, 0); \
            _Pragma("unroll")                                                 \
            for (int mi = 0; mi < 2; ++mi)                                    \
                _Pragma("unroll")                                             \
                for (int nf = 0; nf < 3; ++nf)                                \
                    acc[mi][nf] = __builtin_amdgcn_mfma_f32_16x16x32_bf16(wh[nf], xl[mi], acc[mi][nf], 0, 0, 0); \
            _Pragma("unroll")                                                 \
            for (int mi = 0; mi < 2; ++mi)                                    \
                _Pragma("unroll")                                             \
                for (int nf = 0; nf < 3; ++nf)                                \
                    acc[mi][nf] = __builtin_amdgcn_mfma_f32_16x16x32_bf16(wl[nf], xh[mi], acc[mi][nf], 0, 0, 0); \
        }                                                                     \
    } while (0)

    STAGE(0, 0);
    STAGE(1, 1);

#pragma unroll 1
    for (int kt2 = 0; kt2 < 4; ++kt2) {
        // even k-step (buffer 0): its loads were issued 2 phases ago
        asm volatile("s_waitcnt vmcnt(10)" ::: "memory");
        __builtin_amdgcn_sched_barrier(0);
        __builtin_amdgcn_s_barrier();
        COMPUTE(0);
        __builtin_amdgcn_s_barrier();          // all waves done reading buf0
        if (kt2 < 3) STAGE(0, 2*kt2 + 2);
        // odd k-step (buffer 1)
        if (kt2 < 3) { asm volatile("s_waitcnt vmcnt(10)" ::: "memory"); }
        else         { asm volatile("s_waitcnt vmcnt(0)"  ::: "memory"); }
        __builtin_amdgcn_sched_barrier(0);
        __builtin_amdgcn_s_barrier();
        COMPUTE(1);
        __builtin_amdgcn_s_barrier();          // all waves done reading buf1
        if (kt2 < 3) STAGE(1, 2*kt2 + 3);
    }
#undef STAGE
#undef COMPUTE

    // epilogue: D rows = n, D cols = s (coalesced)
    int sCol = sBase + wm*32 + l15;
    int nRowBase = nBase + wn*48 + (g<<2);
#pragma unroll
    for (int mi = 0; mi < 2; ++mi) {
        int s = sCol + mi*16;
#pragma unroll
        for (int nf = 0; nf < 3; ++nf) {
#pragma unroll
            for (int r = 0; r < 4; ++r) {
                int n = nRowBase + nf*16 + r;
                float val = acc[mi][nf][r] + bias[n];
                int ip = (n * 3641) >> 18;   // n / 72
                int a  = n - ip * 72;
                float res;
                if (ip == 0 || ip == 2)      res = sqrtf(softplus_f(val));
                else if (ip == 1 || ip == 3 || ip == 9 || ip == 11) res = softplus_f(val);
                else                          res = val;
                float* dst = (ip < 8) ? (P + (size_t)ip * SA)
                                      : (out + (size_t)(ip - 7) * SA);
                dst[(size_t)a * S_TOTAL + s] = res;
            }
        }
    }
}

// ---------------- 3. oscillator: order-2 recurrences + rotation scatter ----------------
template<int STEPS>
__device__ __forceinline__ void osc_chunk(
        float& v1a, float& v1b, float& v2a, float& v2b,
        float p1, float q1, float p2, float q2,
        float& acc0, float& acc1, int lane, int lane4) {
#pragma unroll
    for (int i = 0; i < STEPS/2; ++i) {
        {
            const int dt = 2*i;
            v1b = fmaf(p1, v1a, -(q1*v1b));
            v2b = fmaf(p2, v2a, -(q2*v2b));
            float v = v1b + v2b;
            if (dt == 0) {
                acc0 += v;
            } else {
                int addr = (lane4 + (((64-dt)&63)<<2)) & 255;
                float vr = __int_as_float(__builtin_amdgcn_ds_bpermute(addr, __float_as_int(v)));
                bool nw = lane >= dt;
                acc0 += nw ? vr : 0.f;
                acc1 += nw ? 0.f : vr;
            }
        }
        {
            const int dt = 2*i + 1;
            v1a = fmaf(p1, v1b, -(q1*v1a));
            v2a = fmaf(p2, v2b, -(q2*v2a));
            float v = v1a + v2a;
            int addr = (lane4 + (((64-dt)&63)<<2)) & 255;
            float vr = __int_as_float(__builtin_amdgcn_ds_bpermute(addr, __float_as_int(v)));
            bool nw = lane >= dt;
            acc0 += nw ? vr : 0.f;
            acc1 += nw ? 0.f : vr;
        }
    }
}

__global__ __launch_bounds__(256) void osc_kernel(const float* __restrict__ P,
                                                  float* __restrict__ kin) {
    int tid  = threadIdx.x;
    int lane = tid & 63;
    int wv   = tid >> 6;
    int lane4 = lane << 2;
    int sBase = blockIdx.x * 64;
    int a  = blockIdx.y * 2 + (wv >> 1);
    int t0 = (wv & 1) * 300;
    float t0f = (float)t0;

    size_t base = (size_t)a * S_TOTAL + sBase + lane;
    float om1 = P[0*(size_t)SA + base], d1 = P[1*(size_t)SA + base];
    float om2 = P[2*(size_t)SA + base], d2 = P[3*(size_t)SA + base];
    float c1  = P[4*(size_t)SA + base], c2  = P[5*(size_t)SA + base];
    float ph1 = P[6*(size_t)SA + base], ph2 = P[7*(size_t)SA + base];

    float dcf1 = __expf(-0.5f*d1);
    float e1   = c1 * __expf(-0.5f*d1*t0f);
    float s0, c0, so, co;
    __sincosf(fmaf(t0f, om1, ph1), &s0, &c0);
    __sincosf(om1, &so, &co);
    float inv1 = __expf(0.5f*d1);
    float p1 = 2.f*dcf1*co, q1 = dcf1*dcf1;
    float v1a = e1*inv1*(s0*co - c0*so);
    float cs2 = fmaf(2.f*co, co, -1.f), sn2 = 2.f*so*co;
    float v1b = e1*inv1*inv1*(s0*cs2 - c0*sn2);
    float amp1 = fabsf(e1);
    float dq1 = q1*q1; dq1*=dq1; dq1*=dq1; dq1*=dq1; dq1*=dq1;
    float dcf2 = __expf(-0.5f*d2);
    float e2   = c2 * __expf(-0.5f*d2*t0f);
    __sincosf(fmaf(t0f, om2, ph2), &s0, &c0);
    __sincosf(om2, &so, &co);
    float inv2 = __expf(0.5f*d2);
    float p2 = 2.f*dcf2*co, q2 = dcf2*dcf2;
    float v2a = e2*inv2*(s0*co - c0*so);
    cs2 = fmaf(2.f*co, co, -1.f); sn2 = 2.f*so*co;
    float v2b = e2*inv2*inv2*(s0*cs2 - c0*sn2);
    float amp2 = fabsf(e2);
    float dq2 = q2*q2; dq2*=dq2; dq2*=dq2; dq2*=dq2; dq2*=dq2;

    float acc0 = 0.f, acc1 = 0.f;
    float* kinA = kin + (size_t)a * S_TOTAL;
    int jBase = sBase + t0;
    int ran = 0;

#pragma unroll 1
    for (int c = 0; c < 5; ++c) {
        if (__all(fmaxf(amp1, amp2) < AMP_CUT)) break;
        if (c < 4) osc_chunk<64>(v1a, v1b, v2a, v2b, p1, q1, p2, q2, acc0, acc1, lane, lane4);
        else       osc_chunk<44>(v1a, v1b, v2a, v2b, p1, q1, p2, q2, acc0, acc1, lane, lane4);
        int j = jBase + lane;
        if (j < S_TOTAL) unsafeAtomicAdd(&kinA[j], acc0);
        acc0 = acc1; acc1 = 0.f;
        jBase += 64;
        amp1 *= dq1; amp2 *= dq2;
        ran = 1;
        if (jBase >= S_TOTAL) { ran = 0; break; }
    }
    if (ran) {
        int j = jBase + lane;
        if (j < S_TOTAL) unsafeAtomicAdd(&kinA[j], acc0);
    }
}

// ---------------- launch ----------------
extern "C" void kernel_launch(void* const* d_in, const int* in_sizes, int n_in,
                              void* d_out, int out_size, void* d_ws, size_t ws_size,
                              hipStream_t stream) {
    const float* x     = (const float*)d_in[0];
    const float* gamma = (const float*)d_in[1];
    const float* beta  = (const float*)d_in[2];
    const float* W     = (const float*)d_in[3];
    const float* b     = (const float*)d_in[4];
    float* out = (float*)d_out;

    unsigned char* wsb = (unsigned char*)d_ws;
    float* P    = (float*)wsb;                               // 8*SA f32
    unsigned short* Ahi  = (unsigned short*)(wsb + 9437184);
    unsigned short* Alo  = Ahi  + (size_t)S_TOTAL*DDIM;
    unsigned short* WhiT = Alo  + (size_t)S_TOTAL*DDIM;
    unsigned short* WloT = WhiT + (size_t)NPROJ*DDIM;

    prep_kernel<<<dim3(1024 + 432 + 36), dim3(256), 0, stream>>>(x, gamma, beta, W,
                                                                 Ahi, Alo, WhiT, WloT, out);
    gemm_kernel<<<dim3(S_TOTAL/64, NPROJ/96), dim3(256), 0, stream>>>(Ahi, Alo, WhiT, WloT,
                                                                      b, P, out);
    osc_kernel<<<dim3(S_TOTAL/64, AXES/2), dim3(256), 0, stream>>>(P, out);
}

// Round 12
// 59.606 us; speedup vs baseline: 1.6917x; 1.0816x over previous
//
#include <hip/hip_runtime.h>
#include <math.h>

#define S_TOTAL 4096
#define DDIM    512
#define AXES    72
#define NPROJ   864
#define T_PROP  600
#define SA      (S_TOTAL*AXES)
#define LN_EPS  1e-5f
#define AMP_CUT 4e-6f

typedef __attribute__((ext_vector_type(8))) short short8;
typedef __attribute__((ext_vector_type(4))) float f32x4;

__device__ __forceinline__ float softplus_f(float x) {
    return fmaxf(x, 0.f) + log1pf(expf(-fabsf(x)));
}
__device__ __forceinline__ unsigned short bf_hi(float f) {
    return (unsigned short)(__float_as_uint(f) >> 16);
}

// ---------------- 1. fused LN-stats + bf16 split + W^T hi split + kin zero ----------------
__global__ __launch_bounds__(256) void prep_kernel(
        const float* __restrict__ x, const float* __restrict__ gamma,
        const float* __restrict__ beta, const float* __restrict__ W,
        unsigned short* __restrict__ Ahi, unsigned short* __restrict__ Alo,
        unsigned short* __restrict__ WhiT,
        float* __restrict__ kin) {
    __shared__ float Wt[32][33];
    int tid = threadIdx.x;
    int b = blockIdx.x;
    if (b < 1024) {
        int lane = tid & 63, w = tid >> 6;
        int row = b*4 + w;
        const float4* xr = reinterpret_cast<const float4*>(x + (size_t)row * DDIM);
        float4 xv[2] = { xr[lane], xr[lane + 64] };
        float sum = 0.f, ssq = 0.f;
#pragma unroll
        for (int c = 0; c < 2; ++c) {
            sum += (xv[c].x + xv[c].y) + (xv[c].z + xv[c].w);
            ssq += xv[c].x*xv[c].x + xv[c].y*xv[c].y + xv[c].z*xv[c].z + xv[c].w*xv[c].w;
        }
#pragma unroll
        for (int off = 1; off < 64; off <<= 1) {
            sum += __shfl_xor(sum, off);
            ssq += __shfl_xor(ssq, off);
        }
        float m = sum * (1.f/DDIM);
        float r = rsqrtf(ssq * (1.f/DDIM) - m*m + LN_EPS);
        const float4* gp = reinterpret_cast<const float4*>(gamma);
        const float4* bp = reinterpret_cast<const float4*>(beta);
#pragma unroll
        for (int c = 0; c < 2; ++c) {
            float4 gv = gp[lane + 64*c], bv = bp[lane + 64*c];
            float xn[4] = {(xv[c].x-m)*r*gv.x+bv.x, (xv[c].y-m)*r*gv.y+bv.y,
                           (xv[c].z-m)*r*gv.z+bv.z, (xv[c].w-m)*r*gv.w+bv.w};
            ushort4 h4, l4;
            unsigned short* hp = &h4.x;
            unsigned short* lp = &l4.x;
#pragma unroll
            for (int j = 0; j < 4; ++j) {
                unsigned short hi = bf_hi(xn[j]);
                float fhi = __uint_as_float((unsigned)hi << 16);
                hp[j] = hi;
                lp[j] = bf_hi(xn[j] - fhi);
            }
            size_t o = (size_t)row*DDIM + 256*c + lane*4;
            *reinterpret_cast<ushort4*>(&Ahi[o]) = h4;
            *reinterpret_cast<ushort4*>(&Alo[o]) = l4;
        }
    } else if (b < 1456) {
        int wb = b - 1024;
        int bk = wb / 27, bn = wb - bk*27;
        int tx = tid & 31, ty0 = tid >> 5;
#pragma unroll
        for (int rr = 0; rr < 4; ++rr) {
            int ty = ty0 + rr*8;
            Wt[ty][tx] = W[(size_t)(bk*32 + ty)*NPROJ + bn*32 + tx];
        }
        __syncthreads();
#pragma unroll
        for (int rr = 0; rr < 4; ++rr) {
            int ny = ty0 + rr*8;
            int n = bn*32 + ny;
            int k = bk*32 + tx;
            float f = Wt[tx][ny];
            WhiT[(size_t)n*DDIM + k] = bf_hi(f);
        }
    } else {
        int zb = b - 1456;
        float4 z4 = make_float4(0.f, 0.f, 0.f, 0.f);
        float4* kp = reinterpret_cast<float4*>(kin);
#pragma unroll
        for (int i = 0; i < 8; ++i)
            kp[zb*2048 + i*256 + tid] = z4;
    }
}

// ---------------- 2. 2-term split-bf16 MFMA GEMM: global_load_lds + counted vmcnt ----------------
// p = Ahi*Whi + Alo*Whi (dropped Ahi*Wlo term: |err| ~ 1e-3 in p, fine vs threshold).
// LDS per buffer (bytes): Xhi[0,8K) Xlo[8K,16K) Whi[16K,28K); 28 segments x 1KB,
// wave wv owns segs wv*7..wv*7+6. XOR swizzle via pre-swizzled global source.
__global__ __launch_bounds__(256) void gemm_kernel(
        const unsigned short* __restrict__ Ahi, const unsigned short* __restrict__ Alo,
        const unsigned short* __restrict__ WhiT,
        const float* __restrict__ bias,
        float* __restrict__ P, float* __restrict__ out) {
    __shared__ __align__(16) unsigned short ldsArena[2*14336];   // 56 KB

    int tid  = threadIdx.x;
    int lane = tid & 63;
    int wv   = tid >> 6;
    int wm   = wv & 1;
    int wn   = wv >> 1;
    int sBase = blockIdx.x * 64;
    int nBase = blockIdx.y * 96;
    int l15 = lane & 15;
    int g   = lane >> 4;
    int r7  = l15 & 7;

    // stage sources: lane (rr, l7) of segment seg reads global k-slot (l7^rr)
    int rr = lane >> 3;
    int jj = ((lane & 7) ^ rr) * 8;
    const unsigned short* gp[7];
#pragma unroll
    for (int sg = 0; sg < 7; ++sg) {
        int seg = wv*7 + sg;
        const unsigned short* src;
        int row;
        if (seg < 16) {                      // X: seg 0-7 hi, 8-15 lo
            int p = seg >> 3, rg = seg & 7;
            row = sBase + rg*8 + rr;
            src = p ? Alo : Ahi;
        } else {                             // Whi: seg 16-27
            int rg = seg - 16;
            row = nBase + rg*8 + rr;
            src = WhiT;
        }
        gp[sg] = src + (size_t)row*DDIM + jj;
    }

    // precomputed swizzled ds_read offsets
    int koff0 = (g*16) ^ (r7<<4);
    int koff1 = (64 + g*16) ^ (r7<<4);
    int rowXb[2], rowWb[3];
#pragma unroll
    for (int mi = 0; mi < 2; ++mi) rowXb[mi] = (wm*32 + mi*16 + l15) * 128;
#pragma unroll
    for (int nf = 0; nf < 3; ++nf) rowWb[nf] = (wn*48 + nf*16 + l15) * 128;

    f32x4 acc[2][3] = {};

#define STAGE(buf, kt) do {                                                   \
        unsigned short* lb = ldsArena + (buf)*14336 + wv*3584;                \
        _Pragma("unroll")                                                     \
        for (int sg = 0; sg < 7; ++sg)                                        \
            __builtin_amdgcn_global_load_lds(                                 \
                (const __attribute__((address_space(1))) void*)(gp[sg] + (kt)*64), \
                (__attribute__((address_space(3))) void*)(lb + sg*512),       \
                16, 0, 0);                                                    \
    } while (0)

#define COMPUTE(BUF) do {                                                     \
        const char* Bc = (const char*)ldsArena + (BUF)*28672;                 \
        _Pragma("unroll")                                                     \
        for (int kk = 0; kk < 2; ++kk) {                                      \
            int ko = kk ? koff1 : koff0;                                      \
            short8 xh[2], xl[2], wh[3];                                       \
            _Pragma("unroll")                                                 \
            for (int mi = 0; mi < 2; ++mi) {                                  \
                xh[mi] = *reinterpret_cast<const short8*>(Bc + rowXb[mi] + ko);        \
                xl[mi] = *reinterpret_cast<const short8*>(Bc + 8192 + rowXb[mi] + ko); \
            }                                                                 \
            _Pragma("unroll")                                                 \
            for (int nf = 0; nf < 3; ++nf)                                    \
                wh[nf] = *reinterpret_cast<const short8*>(Bc + 16384 + rowWb[nf] + ko); \
            _Pragma("unroll")                                                 \
            for (int mi = 0; mi < 2; ++mi)                                    \
                _Pragma("unroll")                                             \
                for (int nf = 0; nf < 3; ++nf)                                \
                    acc[mi][nf] = __builtin_amdgcn_mfma_f32_16x16x32_bf16(wh[nf], xh[mi], acc[mi][nf], 0, 0, 0); \
            _Pragma("unroll")                                                 \
            for (int mi = 0; mi < 2; ++mi)                                    \
                _Pragma("unroll")                                             \
                for (int nf = 0; nf < 3; ++nf)                                \
                    acc[mi][nf] = __builtin_amdgcn_mfma_f32_16x16x32_bf16(wh[nf], xl[mi], acc[mi][nf], 0, 0, 0); \
        }                                                                     \
    } while (0)

    STAGE(0, 0);
    STAGE(1, 1);

#pragma unroll 1
    for (int kt2 = 0; kt2 < 4; ++kt2) {
        asm volatile("s_waitcnt vmcnt(7)" ::: "memory");
        __builtin_amdgcn_sched_barrier(0);
        __builtin_amdgcn_s_barrier();
        COMPUTE(0);
        __builtin_amdgcn_s_barrier();
        if (kt2 < 3) STAGE(0, 2*kt2 + 2);
        if (kt2 < 3) { asm volatile("s_waitcnt vmcnt(7)" ::: "memory"); }
        else         { asm volatile("s_waitcnt vmcnt(0)" ::: "memory"); }
        __builtin_amdgcn_sched_barrier(0);
        __builtin_amdgcn_s_barrier();
        COMPUTE(1);
        __builtin_amdgcn_s_barrier();
        if (kt2 < 3) STAGE(1, 2*kt2 + 3);
    }
#undef STAGE
#undef COMPUTE

    // epilogue: D rows = n, D cols = s (coalesced)
    int sCol = sBase + wm*32 + l15;
    int nRowBase = nBase + wn*48 + (g<<2);
#pragma unroll
    for (int mi = 0; mi < 2; ++mi) {
        int s = sCol + mi*16;
#pragma unroll
        for (int nf = 0; nf < 3; ++nf) {
#pragma unroll
            for (int r = 0; r < 4; ++r) {
                int n = nRowBase + nf*16 + r;
                float val = acc[mi][nf][r] + bias[n];
                int ip = (n * 3641) >> 18;   // n / 72
                int a  = n - ip * 72;
                float res;
                if (ip == 0 || ip == 2)      res = sqrtf(softplus_f(val));
                else if (ip == 1 || ip == 3 || ip == 9 || ip == 11) res = softplus_f(val);
                else                          res = val;
                float* dst = (ip < 8) ? (P + (size_t)ip * SA)
                                      : (out + (size_t)(ip - 7) * SA);
                dst[(size_t)a * S_TOTAL + s] = res;
            }
        }
    }
}

// ---------------- 3. oscillator: order-2 recurrences + rotation scatter ----------------
template<int STEPS>
__device__ __forceinline__ void osc_chunk(
        float& v1a, float& v1b, float& v2a, float& v2b,
        float p1, float q1, float p2, float q2,
        float& acc0, float& acc1, int lane, int lane4) {
#pragma unroll
    for (int i = 0; i < STEPS/2; ++i) {
        {
            const int dt = 2*i;
            v1b = fmaf(p1, v1a, -(q1*v1b));
            v2b = fmaf(p2, v2a, -(q2*v2b));
            float v = v1b + v2b;
            if (dt == 0) {
                acc0 += v;
            } else {
                int addr = (lane4 + (((64-dt)&63)<<2)) & 255;
                float vr = __int_as_float(__builtin_amdgcn_ds_bpermute(addr, __float_as_int(v)));
                bool nw = lane >= dt;
                acc0 += nw ? vr : 0.f;
                acc1 += nw ? 0.f : vr;
            }
        }
        {
            const int dt = 2*i + 1;
            v1a = fmaf(p1, v1b, -(q1*v1a));
            v2a = fmaf(p2, v2b, -(q2*v2a));
            float v = v1a + v2a;
            int addr = (lane4 + (((64-dt)&63)<<2)) & 255;
            float vr = __int_as_float(__builtin_amdgcn_ds_bpermute(addr, __float_as_int(v)));
            bool nw = lane >= dt;
            acc0 += nw ? vr : 0.f;
            acc1 += nw ? 0.f : vr;
        }
    }
}

__global__ __launch_bounds__(256) void osc_kernel(const float* __restrict__ P,
                                                  float* __restrict__ kin) {
    int tid  = threadIdx.x;
    int lane = tid & 63;
    int wv   = tid >> 6;
    int lane4 = lane << 2;
    int sBase = blockIdx.x * 64;
    int a  = blockIdx.y * 2 + (wv >> 1);
    int t0 = (wv & 1) * 300;
    float t0f = (float)t0;
    if (sBase + t0 >= S_TOTAL) return;

    size_t base = (size_t)a * S_TOTAL + sBase + lane;
    float om1 = P[0*(size_t)SA + base], d1 = P[1*(size_t)SA + base];
    float om2 = P[2*(size_t)SA + base], d2 = P[3*(size_t)SA + base];
    float c1  = P[4*(size_t)SA + base], c2  = P[5*(size_t)SA + base];
    float ph1 = P[6*(size_t)SA + base], ph2 = P[7*(size_t)SA + base];

    float dcf1 = __expf(-0.5f*d1);
    float e1   = c1 * __expf(-0.5f*d1*t0f);
    float s0, c0, so, co;
    __sincosf(fmaf(t0f, om1, ph1), &s0, &c0);
    __sincosf(om1, &so, &co);
    float inv1 = __expf(0.5f*d1);
    float p1 = 2.f*dcf1*co, q1 = dcf1*dcf1;
    float v1a = e1*inv1*(s0*co - c0*so);
    float cs2 = fmaf(2.f*co, co, -1.f), sn2 = 2.f*so*co;
    float v1b = e1*inv1*inv1*(s0*cs2 - c0*sn2);
    float amp1 = fabsf(e1);
    float dq1 = q1*q1; dq1*=dq1; dq1*=dq1; dq1*=dq1; dq1*=dq1;
    float dcf2 = __expf(-0.5f*d2);
    float e2   = c2 * __expf(-0.5f*d2*t0f);
    __sincosf(fmaf(t0f, om2, ph2), &s0, &c0);
    __sincosf(om2, &so, &co);
    float inv2 = __expf(0.5f*d2);
    float p2 = 2.f*dcf2*co, q2 = dcf2*dcf2;
    float v2a = e2*inv2*(s0*co - c0*so);
    cs2 = fmaf(2.f*co, co, -1.f); sn2 = 2.f*so*co;
    float v2b = e2*inv2*inv2*(s0*cs2 - c0*sn2);
    float amp2 = fabsf(e2);
    float dq2 = q2*q2; dq2*=dq2; dq2*=dq2; dq2*=dq2; dq2*=dq2;

    float acc0 = 0.f, acc1 = 0.f;
    float* kinA = kin + (size_t)a * S_TOTAL;
    int jBase = sBase + t0;
    int ran = 0;

#pragma unroll 1
    for (int c = 0; c < 5; ++c) {
        if (__all(fmaxf(amp1, amp2) < AMP_CUT)) break;
        if (c < 4) osc_chunk<64>(v1a, v1b, v2a, v2b, p1, q1, p2, q2, acc0, acc1, lane, lane4);
        else       osc_chunk<44>(v1a, v1b, v2a, v2b, p1, q1, p2, q2, acc0, acc1, lane, lane4);
        int j = jBase + lane;
        if (j < S_TOTAL) unsafeAtomicAdd(&kinA[j], acc0);
        acc0 = acc1; acc1 = 0.f;
        jBase += 64;
        amp1 *= dq1; amp2 *= dq2;
        ran = 1;
        if (jBase >= S_TOTAL) { ran = 0; break; }
    }
    if (ran) {
        int j = jBase + lane;
        if (j < S_TOTAL) unsafeAtomicAdd(&kinA[j], acc0);
    }
}

// ---------------- launch ----------------
extern "C" void kernel_launch(void* const* d_in, const int* in_sizes, int n_in,
                              void* d_out, int out_size, void* d_ws, size_t ws_size,
                              hipStream_t stream) {
    const float* x     = (const float*)d_in[0];
    const float* gamma = (const float*)d_in[1];
    const float* beta  = (const float*)d_in[2];
    const float* W     = (const float*)d_in[3];
    const float* b     = (const float*)d_in[4];
    float* out = (float*)d_out;

    unsigned char* wsb = (unsigned char*)d_ws;
    float* P    = (float*)wsb;                               // 8*SA f32
    unsigned short* Ahi  = (unsigned short*)(wsb + 9437184);
    unsigned short* Alo  = Ahi  + (size_t)S_TOTAL*DDIM;
    unsigned short* WhiT = Alo  + (size_t)S_TOTAL*DDIM;

    prep_kernel<<<dim3(1024 + 432 + 36), dim3(256), 0, stream>>>(x, gamma, beta, W,
                                                                 Ahi, Alo, WhiT, out);
    gemm_kernel<<<dim3(S_TOTAL/64, NPROJ/96), dim3(256), 0, stream>>>(Ahi, Alo, WhiT,
                                                                      b, P, out);
    osc_kernel<<<dim3(S_TOTAL/64, AXES/2), dim3(256), 0, stream>>>(P, out);
}

// Round 13
// 52.028 us; speedup vs baseline: 1.9381x; 1.1456x over previous
//
#include <hip/hip_runtime.h>
#include <math.h>

#define S_TOTAL 4096
#define DDIM    512
#define AXES    72
#define NPROJ   864
#define T_PROP  600
#define SA      (S_TOTAL*AXES)
#define LN_EPS  1e-5f
#define AMP_CUT 4e-6f

typedef __attribute__((ext_vector_type(8))) short short8;
typedef __attribute__((ext_vector_type(4))) float f32x4;

__device__ __forceinline__ float softplus_f(float x) {
    return fmaxf(x, 0.f) + log1pf(expf(-fabsf(x)));
}
__device__ __forceinline__ unsigned short bf_hi(float f) {
    return (unsigned short)(__float_as_uint(f) >> 16);
}

// ---------------- 1. fused LN-stats + bf16 split + W^T hi split + kin zero ----------------
__global__ __launch_bounds__(256) void prep_kernel(
        const float* __restrict__ x, const float* __restrict__ gamma,
        const float* __restrict__ beta, const float* __restrict__ W,
        unsigned short* __restrict__ Ahi, unsigned short* __restrict__ Alo,
        unsigned short* __restrict__ WhiT,
        float* __restrict__ kin) {
    __shared__ float Wt[32][33];
    int tid = threadIdx.x;
    int b = blockIdx.x;
    if (b < 1024) {
        int lane = tid & 63, w = tid >> 6;
        int row = b*4 + w;
        const float4* xr = reinterpret_cast<const float4*>(x + (size_t)row * DDIM);
        float4 xv[2] = { xr[lane], xr[lane + 64] };
        float sum = 0.f, ssq = 0.f;
#pragma unroll
        for (int c = 0; c < 2; ++c) {
            sum += (xv[c].x + xv[c].y) + (xv[c].z + xv[c].w);
            ssq += xv[c].x*xv[c].x + xv[c].y*xv[c].y + xv[c].z*xv[c].z + xv[c].w*xv[c].w;
        }
#pragma unroll
        for (int off = 1; off < 64; off <<= 1) {
            sum += __shfl_xor(sum, off);
            ssq += __shfl_xor(ssq, off);
        }
        float m = sum * (1.f/DDIM);
        float r = rsqrtf(ssq * (1.f/DDIM) - m*m + LN_EPS);
        const float4* gp = reinterpret_cast<const float4*>(gamma);
        const float4* bp = reinterpret_cast<const float4*>(beta);
#pragma unroll
        for (int c = 0; c < 2; ++c) {
            float4 gv = gp[lane + 64*c], bv = bp[lane + 64*c];
            float xn[4] = {(xv[c].x-m)*r*gv.x+bv.x, (xv[c].y-m)*r*gv.y+bv.y,
                           (xv[c].z-m)*r*gv.z+bv.z, (xv[c].w-m)*r*gv.w+bv.w};
            ushort4 h4, l4;
            unsigned short* hp = &h4.x;
            unsigned short* lp = &l4.x;
#pragma unroll
            for (int j = 0; j < 4; ++j) {
                unsigned short hi = bf_hi(xn[j]);
                float fhi = __uint_as_float((unsigned)hi << 16);
                hp[j] = hi;
                lp[j] = bf_hi(xn[j] - fhi);
            }
            size_t o = (size_t)row*DDIM + 256*c + lane*4;
            *reinterpret_cast<ushort4*>(&Ahi[o]) = h4;
            *reinterpret_cast<ushort4*>(&Alo[o]) = l4;
        }
    } else if (b < 1456) {
        int wb = b - 1024;
        int bk = wb / 27, bn = wb - bk*27;
        int tx = tid & 31, ty0 = tid >> 5;
#pragma unroll
        for (int rr = 0; rr < 4; ++rr) {
            int ty = ty0 + rr*8;
            Wt[ty][tx] = W[(size_t)(bk*32 + ty)*NPROJ + bn*32 + tx];
        }
        __syncthreads();
#pragma unroll
        for (int rr = 0; rr < 4; ++rr) {
            int ny = ty0 + rr*8;
            int n = bn*32 + ny;
            int k = bk*32 + tx;
            float f = Wt[tx][ny];
            WhiT[(size_t)n*DDIM + k] = bf_hi(f);
        }
    } else {
        int zb = b - 1456;
        float4 z4 = make_float4(0.f, 0.f, 0.f, 0.f);
        float4* kp = reinterpret_cast<float4*>(kin);
#pragma unroll
        for (int i = 0; i < 8; ++i)
            kp[zb*2048 + i*256 + tid] = z4;
    }
}

// ---------------- 2. 2-term split-bf16 MFMA GEMM, 32x96 tile, 4 blocks/CU ----------------
// p = (Ahi + Alo)*Whi. Tile 32s x 96n, 4 waves each 16s x 48n -> 1152 blocks,
// LDS 2 x 20KB -> 4 blocks/CU = 16 waves/CU (2x R12's residency).
// LDS per buffer (bytes): Xhi[0,4K) Xlo[4K,8K) Whi[8K,20K); 20 segs x 1KB,
// wave wv owns segs wv*5..wv*5+4. XOR swizzle via pre-swizzled global source;
// counted-vmcnt double buffer.
__global__ __launch_bounds__(256) void gemm_kernel(
        const unsigned short* __restrict__ Ahi, const unsigned short* __restrict__ Alo,
        const unsigned short* __restrict__ WhiT,
        const float* __restrict__ bias,
        float* __restrict__ P, float* __restrict__ out) {
    __shared__ __align__(16) unsigned short ldsArena[2*10240];   // 40 KB

    int tid  = threadIdx.x;
    int lane = tid & 63;
    int wv   = tid >> 6;
    int wm   = wv & 1;        // s-half (16 rows)
    int wn   = wv >> 1;       // n-half (48 cols)
    int sBase = blockIdx.x * 32;
    int nBase = blockIdx.y * 96;
    int l15 = lane & 15;
    int g   = lane >> 4;
    int r7  = l15 & 7;

    // stage sources: lane (rr, l7) of segment seg reads global k-slot (l7^rr)
    int rr = lane >> 3;
    int jj = ((lane & 7) ^ rr) * 8;
    const unsigned short* gp[5];
#pragma unroll
    for (int sg = 0; sg < 5; ++sg) {
        int seg = wv*5 + sg;
        const unsigned short* src;
        int row;
        if (seg < 8) {                       // X: seg 0-3 hi, 4-7 lo
            int p = seg >> 2, rg = seg & 3;
            row = sBase + rg*8 + rr;
            src = p ? Alo : Ahi;
        } else {                             // Whi: seg 8-19
            int rg = seg - 8;
            row = nBase + rg*8 + rr;
            src = WhiT;
        }
        gp[sg] = src + (size_t)row*DDIM + jj;
    }

    // precomputed swizzled ds_read offsets
    int koff0 = (g*16) ^ (r7<<4);
    int koff1 = (64 + g*16) ^ (r7<<4);
    int rowXb = (wm*16 + l15) * 128;
    int rowWb[3];
#pragma unroll
    for (int nf = 0; nf < 3; ++nf) rowWb[nf] = (wn*48 + nf*16 + l15) * 128;

    f32x4 acc[3] = {};

#define STAGE(buf, kt) do {                                                   \
        unsigned short* lb = ldsArena + (buf)*10240 + wv*2560;                \
        _Pragma("unroll")                                                     \
        for (int sg = 0; sg < 5; ++sg)                                        \
            __builtin_amdgcn_global_load_lds(                                 \
                (const __attribute__((address_space(1))) void*)(gp[sg] + (kt)*64), \
                (__attribute__((address_space(3))) void*)(lb + sg*512),       \
                16, 0, 0);                                                    \
    } while (0)

#define COMPUTE(BUF) do {                                                     \
        const char* Bc = (const char*)ldsArena + (BUF)*20480;                 \
        _Pragma("unroll")                                                     \
        for (int kk = 0; kk < 2; ++kk) {                                      \
            int ko = kk ? koff1 : koff0;                                      \
            short8 xh, xl, wh[3];                                             \
            xh = *reinterpret_cast<const short8*>(Bc + rowXb + ko);           \
            xl = *reinterpret_cast<const short8*>(Bc + 4096 + rowXb + ko);    \
            _Pragma("unroll")                                                 \
            for (int nf = 0; nf < 3; ++nf)                                    \
                wh[nf] = *reinterpret_cast<const short8*>(Bc + 8192 + rowWb[nf] + ko); \
            _Pragma("unroll")                                                 \
            for (int nf = 0; nf < 3; ++nf)                                    \
                acc[nf] = __builtin_amdgcn_mfma_f32_16x16x32_bf16(wh[nf], xh, acc[nf], 0, 0, 0); \
            _Pragma("unroll")                                                 \
            for (int nf = 0; nf < 3; ++nf)                                    \
                acc[nf] = __builtin_amdgcn_mfma_f32_16x16x32_bf16(wh[nf], xl, acc[nf], 0, 0, 0); \
        }                                                                     \
    } while (0)

    STAGE(0, 0);
    STAGE(1, 1);

#pragma unroll 1
    for (int kt2 = 0; kt2 < 4; ++kt2) {
        asm volatile("s_waitcnt vmcnt(5)" ::: "memory");
        __builtin_amdgcn_sched_barrier(0);
        __builtin_amdgcn_s_barrier();
        COMPUTE(0);
        __builtin_amdgcn_s_barrier();
        if (kt2 < 3) STAGE(0, 2*kt2 + 2);
        if (kt2 < 3) { asm volatile("s_waitcnt vmcnt(5)" ::: "memory"); }
        else         { asm volatile("s_waitcnt vmcnt(0)" ::: "memory"); }
        __builtin_amdgcn_sched_barrier(0);
        __builtin_amdgcn_s_barrier();
        COMPUTE(1);
        __builtin_amdgcn_s_barrier();
        if (kt2 < 3) STAGE(1, 2*kt2 + 3);
    }
#undef STAGE
#undef COMPUTE

    // epilogue: D rows = n, D cols = s (coalesced); 12 outputs/thread
    int s = sBase + wm*16 + l15;
    int nRowBase = nBase + wn*48 + (g<<2);
#pragma unroll
    for (int nf = 0; nf < 3; ++nf) {
#pragma unroll
        for (int r = 0; r < 4; ++r) {
            int n = nRowBase + nf*16 + r;
            float val = acc[nf][r] + bias[n];
            int ip = (n * 3641) >> 18;   // n / 72
            int a  = n - ip * 72;
            float res;
            if (ip == 0 || ip == 2)      res = sqrtf(softplus_f(val));
            else if (ip == 1 || ip == 3 || ip == 9 || ip == 11) res = softplus_f(val);
            else                          res = val;
            float* dst = (ip < 8) ? (P + (size_t)ip * SA)
                                  : (out + (size_t)(ip - 7) * SA);
            dst[(size_t)a * S_TOTAL + s] = res;
        }
    }
}

// ---------------- 3. oscillator: order-2 recurrences + rotation scatter ----------------
template<int STEPS>
__device__ __forceinline__ void osc_chunk(
        float& v1a, float& v1b, float& v2a, float& v2b,
        float p1, float q1, float p2, float q2,
        float& acc0, float& acc1, int lane, int lane4) {
#pragma unroll
    for (int i = 0; i < STEPS/2; ++i) {
        {
            const int dt = 2*i;
            v1b = fmaf(p1, v1a, -(q1*v1b));
            v2b = fmaf(p2, v2a, -(q2*v2b));
            float v = v1b + v2b;
            if (dt == 0) {
                acc0 += v;
            } else {
                int addr = (lane4 + (((64-dt)&63)<<2)) & 255;
                float vr = __int_as_float(__builtin_amdgcn_ds_bpermute(addr, __float_as_int(v)));
                bool nw = lane >= dt;
                acc0 += nw ? vr : 0.f;
                acc1 += nw ? 0.f : vr;
            }
        }
        {
            const int dt = 2*i + 1;
            v1a = fmaf(p1, v1b, -(q1*v1a));
            v2a = fmaf(p2, v2b, -(q2*v2a));
            float v = v1a + v2a;
            int addr = (lane4 + (((64-dt)&63)<<2)) & 255;
            float vr = __int_as_float(__builtin_amdgcn_ds_bpermute(addr, __float_as_int(v)));
            bool nw = lane >= dt;
            acc0 += nw ? vr : 0.f;
            acc1 += nw ? 0.f : vr;
        }
    }
}

__global__ __launch_bounds__(256) void osc_kernel(const float* __restrict__ P,
                                                  float* __restrict__ kin) {
    int tid  = threadIdx.x;
    int lane = tid & 63;
    int wv   = tid >> 6;
    int lane4 = lane << 2;
    int sBase = blockIdx.x * 64;
    int a  = blockIdx.y * 2 + (wv >> 1);
    int t0 = (wv & 1) * 300;
    float t0f = (float)t0;
    if (sBase + t0 >= S_TOTAL) return;

    size_t base = (size_t)a * S_TOTAL + sBase + lane;
    float om1 = P[0*(size_t)SA + base], d1 = P[1*(size_t)SA + base];
    float om2 = P[2*(size_t)SA + base], d2 = P[3*(size_t)SA + base];
    float c1  = P[4*(size_t)SA + base], c2  = P[5*(size_t)SA + base];
    float ph1 = P[6*(size_t)SA + base], ph2 = P[7*(size_t)SA + base];

    float dcf1 = __expf(-0.5f*d1);
    float e1   = c1 * __expf(-0.5f*d1*t0f);
    float s0, c0, so, co;
    __sincosf(fmaf(t0f, om1, ph1), &s0, &c0);
    __sincosf(om1, &so, &co);
    float inv1 = __expf(0.5f*d1);
    float p1 = 2.f*dcf1*co, q1 = dcf1*dcf1;
    float v1a = e1*inv1*(s0*co - c0*so);
    float cs2 = fmaf(2.f*co, co, -1.f), sn2 = 2.f*so*co;
    float v1b = e1*inv1*inv1*(s0*cs2 - c0*sn2);
    float amp1 = fabsf(e1);
    float dq1 = q1*q1; dq1*=dq1; dq1*=dq1; dq1*=dq1; dq1*=dq1;
    float dcf2 = __expf(-0.5f*d2);
    float e2   = c2 * __expf(-0.5f*d2*t0f);
    __sincosf(fmaf(t0f, om2, ph2), &s0, &c0);
    __sincosf(om2, &so, &co);
    float inv2 = __expf(0.5f*d2);
    float p2 = 2.f*dcf2*co, q2 = dcf2*dcf2;
    float v2a = e2*inv2*(s0*co - c0*so);
    cs2 = fmaf(2.f*co, co, -1.f); sn2 = 2.f*so*co;
    float v2b = e2*inv2*inv2*(s0*cs2 - c0*sn2);
    float amp2 = fabsf(e2);
    float dq2 = q2*q2; dq2*=dq2; dq2*=dq2; dq2*=dq2; dq2*=dq2;

    float acc0 = 0.f, acc1 = 0.f;
    float* kinA = kin + (size_t)a * S_TOTAL;
    int jBase = sBase + t0;
    int ran = 0;

#pragma unroll 1
    for (int c = 0; c < 5; ++c) {
        if (__all(fmaxf(amp1, amp2) < AMP_CUT)) break;
        if (c < 4) osc_chunk<64>(v1a, v1b, v2a, v2b, p1, q1, p2, q2, acc0, acc1, lane, lane4);
        else       osc_chunk<44>(v1a, v1b, v2a, v2b, p1, q1, p2, q2, acc0, acc1, lane, lane4);
        int j = jBase + lane;
        if (j < S_TOTAL) unsafeAtomicAdd(&kinA[j], acc0);
        acc0 = acc1; acc1 = 0.f;
        jBase += 64;
        amp1 *= dq1; amp2 *= dq2;
        ran = 1;
        if (jBase >= S_TOTAL) { ran = 0; break; }
    }
    if (ran) {
        int j = jBase + lane;
        if (j < S_TOTAL) unsafeAtomicAdd(&kinA[j], acc0);
    }
}

// ---------------- launch ----------------
extern "C" void kernel_launch(void* const* d_in, const int* in_sizes, int n_in,
                              void* d_out, int out_size, void* d_ws, size_t ws_size,
                              hipStream_t stream) {
    const float* x     = (const float*)d_in[0];
    const float* gamma = (const float*)d_in[1];
    const float* beta  = (const float*)d_in[2];
    const float* W     = (const float*)d_in[3];
    const float* b     = (const float*)d_in[4];
    float* out = (float*)d_out;

    unsigned char* wsb = (unsigned char*)d_ws;
    float* P    = (float*)wsb;                               // 8*SA f32
    unsigned short* Ahi  = (unsigned short*)(wsb + 9437184);
    unsigned short* Alo  = Ahi  + (size_t)S_TOTAL*DDIM;
    unsigned short* WhiT = Alo  + (size_t)S_TOTAL*DDIM;

    prep_kernel<<<dim3(1024 + 432 + 36), dim3(256), 0, stream>>>(x, gamma, beta, W,
                                                                 Ahi, Alo, WhiT, out);
    gemm_kernel<<<dim3(S_TOTAL/32, NPROJ/96), dim3(256), 0, stream>>>(Ahi, Alo, WhiT,
                                                                      b, P, out);
    osc_kernel<<<dim3(S_TOTAL/64, AXES/2), dim3(256), 0, stream>>>(P, out);
}